// Round 5
// baseline (296.139 us; speedup 1.0000x reference)
//
#include <hip/hip_runtime.h>
#include <hip/hip_bf16.h>

typedef __attribute__((ext_vector_type(4))) float f32x4;
typedef __attribute__((ext_vector_type(8))) short s16x8;
typedef __attribute__((ext_vector_type(4))) unsigned short u16x4;
typedef __attribute__((ext_vector_type(8))) __bf16 bf16x8;

#define HDIM 512
#define SEQ  2048
#define NB   64
#define BM   64
#define NBLK 256                 // persistent: 1 block/CU, 8 tiles each
#define TPB  8                   // tiles per block
#define CPB  (SEQ / BM)          // 32 chunks per batch

// round-to-nearest-even fp32 -> bf16 bits
static __device__ __forceinline__ unsigned short f2bf(float f) {
  unsigned u = __float_as_uint(f);
  u += 0x7fffu + ((u >> 16) & 1u);
  return (unsigned short)(u >> 16);
}
static __device__ __forceinline__ float bf2f(unsigned short v) {
  return __uint_as_float(((unsigned)v) << 16);
}

static __device__ __forceinline__ f32x4 mfma16(s16x8 a, s16x8 b, f32x4 c) {
  return __builtin_amdgcn_mfma_f32_16x16x32_bf16(
      __builtin_bit_cast(bf16x8, a), __builtin_bit_cast(bf16x8, b), c, 0, 0, 0);
}

// ---------------- kernel 0a: W1 fp32 -> bf16, k-step-major -------------------
// 16B chunk id = kk*2048 + n*4 + r4 holds W1[n][kk*32 + r4*8 .. +8] as bf16.
__global__ void convert_w1(const float* __restrict__ w1,
                           unsigned short* __restrict__ o) {
  int id = blockIdx.x * 256 + threadIdx.x;   // 32768 chunks of 16B
  int kk = id >> 11, n = (id >> 2) & 511, r4 = id & 3;
  const float* src = w1 + (long)n * HDIM + kk * 32 + r4 * 8;
  f32x4 v0 = *(const f32x4*)src;
  f32x4 v1 = *(const f32x4*)(src + 4);
  u16x4 a, b;
  a.x = f2bf(v0.x); a.y = f2bf(v0.y); a.z = f2bf(v0.z); a.w = f2bf(v0.w);
  b.x = f2bf(v1.x); b.y = f2bf(v1.y); b.z = f2bf(v1.z); b.w = f2bf(v1.w);
  unsigned short* dst = o + (long)id * 8;
  *(u16x4*)dst = a;
  *(u16x4*)(dst + 4) = b;
}

// ---------------- kernel 0b: z[b][o] = dec[b]·W2[o] + b2[o] + b1[o] ----------
__global__ void zproj(const float* __restrict__ dec, const float* __restrict__ W2,
                      const float* __restrict__ b1, const float* __restrict__ b2,
                      float* __restrict__ zfull) {
  int b = blockIdx.x, oc = blockIdx.y, tid = threadIdx.x;
  int o = oc * 256 + tid;
  __shared__ float d_s[HDIM];
  d_s[tid] = dec[b * HDIM + tid];
  d_s[tid + 256] = dec[b * HDIM + tid + 256];
  __syncthreads();
  const float* w = W2 + (long)o * HDIM;
  float s = 0.f;
#pragma unroll 4
  for (int k = 0; k < HDIM; k += 4) {
    f32x4 v = *(const f32x4*)(w + k);
    s += v.x * d_s[k] + v.y * d_s[k + 1] + v.z * d_s[k + 2] + v.w * d_s[k + 3];
  }
  zfull[b * HDIM + o] = s + b1[o] + b2[o];
}

// ------ kernel 1: persistent fused GEMM + tanh + V-dot + softmax partials ----
// 256 blocks x 8 tiles. A tile (64x512 bf16) double-buffered in LDS; staging
// of tile i+1 interleaved into K-loop of tile i. B via 1-deep reg dbuf.
__global__ __launch_bounds__(512, 2)
void gemm_fused(const float* __restrict__ enc, const unsigned short* __restrict__ w1k,
                const float* __restrict__ zfull, const float* __restrict__ V,
                const float* __restrict__ bv, float* __restrict__ scores,
                unsigned short* __restrict__ pctx, float* __restrict__ ml) {
  __shared__ __align__(16) char pool[153856];
  // [0]       A buf0 (64 KiB)   [65536] A buf1 (64 KiB)
  float* zbuf = (float*)(pool + 131072);   // 512 f
  float* vbuf = (float*)(pool + 133120);   // 512 f
  float* red  = (float*)(pool + 135168);   // 8*64 f
  float* plds = (float*)(pool + 137216);   // 64 f
  float* pcr  = (float*)(pool + 137472);   // 8*512 f (16 KiB)

  const int tid = threadIdx.x;
  const int wid = tid >> 6;
  const int lane = tid & 63;
  const int r4 = lane >> 4, c15 = lane & 15, c7 = c15 & 7;

  vbuf[tid] = V[tid];

  // A staging addressing (const per thread)
  const int qf32 = tid & 127;          // 16B fp32 chunk within row
  const int rbase = tid >> 7;          // row sub-index
  const int qch = qf32 >> 1, half = qf32 & 1;

  // ---- prologue: stage tile 0 into buf0, load zbuf for tile 0 ----
  {
    long T0 = blockIdx.x;
    zbuf[tid] = zfull[(int)(T0 >> 5) * HDIM + tid];
    const float* Ablk = enc + (T0 * BM) * HDIM;
#pragma unroll
    for (int j = 0; j < 16; ++j) {
      const int row = j * 4 + rbase;
      f32x4 v = *(const f32x4*)(Ablk + (long)row * HDIM + qf32 * 4);
      u16x4 pk;
      pk.x = f2bf(v.x); pk.y = f2bf(v.y); pk.z = f2bf(v.z); pk.w = f2bf(v.w);
      *(u16x4*)(pool + row * 1024 + ((qch ^ (row & 7)) * 16) + half * 8) = pk;
    }
  }
  __syncthreads();

  // A-fragment read constants (XOR swizzle): phys chunk p = (kk*4+r4) ^ c7
  const int rs = r4 ^ (c7 & 3), kb = c7 >> 2;
  const int a0 = c15 * 1024 + rs * 16 + kb * 64;        // even kk
  const int a1 = c15 * 1024 + rs * 16 + (kb ^ 1) * 64;  // odd  kk
  const unsigned short* bpbase = w1k + (wid * 64 + c15) * 32 + r4 * 8;

  int cur = 0;

  for (int i = 0; i < TPB; ++i) {
    const long T = (long)blockIdx.x + (long)NBLK * i;
    const long m0 = T * BM;
    const char* Ab = pool + cur * 65536;
    char* Aw = pool + (cur ^ 1) * 65536;
    const float* Anext = enc + ((T + NBLK) * BM) * HDIM;
    const bool more = (i < TPB - 1);

    f32x4 acc[4][4] = {};
    s16x8 bA[4], bB[4];
    f32x4 st[4][4];

    // B prefetch kk=0
#pragma unroll
    for (int nf = 0; nf < 4; ++nf) bA[nf] = *(const s16x8*)(bpbase + nf * 512);

    // ---- K-loop (barrier-free) with interleaved A-staging of tile i+1 ----
#pragma unroll
    for (int kt = 0; kt < 8; ++kt) {
      const int k0 = 2 * kt, k1 = k0 + 1;
      // issue staging batch kt (4 rows-of-4 loads) for tile i+1
      if (more && kt < 4) {
#pragma unroll
        for (int u = 0; u < 4; ++u) {
          const int row = (kt * 4 + u) * 4 + rbase;
          st[kt][u] = *(const f32x4*)(Anext + (long)row * HDIM + qf32 * 4);
        }
      }
      // B(k1) load; compute with bA(k0)
#pragma unroll
      for (int nf = 0; nf < 4; ++nf)
        bB[nf] = *(const s16x8*)(bpbase + k1 * 16384 + nf * 512);
      {
        s16x8 af[4];
        const int ab = a0 + kt * 128;
#pragma unroll
        for (int mf = 0; mf < 4; ++mf)
          af[mf] = *(const s16x8*)(Ab + ab + mf * 16384);
#pragma unroll
        for (int mf = 0; mf < 4; ++mf)
#pragma unroll
          for (int nf = 0; nf < 4; ++nf)
            acc[mf][nf] = mfma16(af[mf], bA[nf], acc[mf][nf]);
      }
      // write staging batch kt-2 (loads had ~2 phases to land)
      if (more && kt >= 2 && kt < 6) {
        const int bt = kt - 2;
#pragma unroll
        for (int u = 0; u < 4; ++u) {
          const int row = (bt * 4 + u) * 4 + rbase;
          f32x4 v = st[bt][u];
          u16x4 pk;
          pk.x = f2bf(v.x); pk.y = f2bf(v.y); pk.z = f2bf(v.z); pk.w = f2bf(v.w);
          *(u16x4*)(Aw + row * 1024 + ((qch ^ (row & 7)) * 16) + half * 8) = pk;
        }
      }
      // B(k0+2) load; compute with bB(k1)
      if (kt < 7) {
#pragma unroll
        for (int nf = 0; nf < 4; ++nf)
          bA[nf] = *(const s16x8*)(bpbase + (k0 + 2) * 16384 + nf * 512);
      }
      {
        s16x8 af[4];
        const int ab = a1 + kt * 128;
#pragma unroll
        for (int mf = 0; mf < 4; ++mf)
          af[mf] = *(const s16x8*)(Ab + ab + mf * 16384);
#pragma unroll
        for (int mf = 0; mf < 4; ++mf)
#pragma unroll
          for (int nf = 0; nf < 4; ++nf)
            acc[mf][nf] = mfma16(af[mf], bB[nf], acc[mf][nf]);
      }
    }

    // ---- epilogue 1: per-thread tanh/V reduction -> red ----
    // C/D layout (16x16x32): col = lane&15, row = (lane>>4)*4 + j   [m89/m91]
#pragma unroll
    for (int mf = 0; mf < 4; ++mf) {
#pragma unroll
      for (int j = 0; j < 4; ++j) {
        float s = 0.f;
#pragma unroll
        for (int nf = 0; nf < 4; ++nf) {
          const int n = wid * 64 + nf * 16 + c15;
          float x = acc[mf][nf][j] + zbuf[n];
          float e = __expf(2.f * x);
          float t = 1.f - 2.f * __builtin_amdgcn_rcpf(e + 1.f);  // tanh(x)
          s += t * vbuf[n];
        }
        s += __shfl_xor(s, 1); s += __shfl_xor(s, 2);
        s += __shfl_xor(s, 4); s += __shfl_xor(s, 8);
        if (c15 == 0) red[wid * BM + mf * 16 + r4 * 4 + j] = s;
      }
    }
    __syncthreads();

    // ---- epilogue 2: wave 0 -> raw scores + local softmax stats ----
    if (tid < BM) {
      float s = 0.f;
#pragma unroll
      for (int w = 0; w < 8; ++w) s += red[w * BM + tid];
      s += bv[0];
      scores[m0 + tid] = s;
      float mc = s;
#pragma unroll
      for (int off = 1; off < 64; off <<= 1) mc = fmaxf(mc, __shfl_xor(mc, off));
      float p = __expf(s - mc);
      plds[tid] = p;
      float lc = p;
#pragma unroll
      for (int off = 1; off < 64; off <<= 1) lc += __shfl_xor(lc, off);
      if (tid == 0) { ml[T * 2] = mc; ml[T * 2 + 1] = lc; }
    }
    __syncthreads();

    // ---- epilogue 3: pctx[h] = sum_s p[s]*A[s][h], vector LDS reads ----
    {
      float c8[8] = {};
#pragma unroll
      for (int rr = 0; rr < 8; ++rr) {
        const int r = wid * 8 + rr;
        s16x8 v = *(const s16x8*)(Ab + r * 1024 + ((lane ^ rr) * 16));
        const float p = plds[r];
#pragma unroll
        for (int e = 0; e < 8; ++e)
          c8[e] += p * bf2f((unsigned short)v[e]);
      }
      f32x4 w0, w1;
      w0.x = c8[0]; w0.y = c8[1]; w0.z = c8[2]; w0.w = c8[3];
      w1.x = c8[4]; w1.y = c8[5]; w1.z = c8[6]; w1.w = c8[7];
      *(f32x4*)((char*)pcr + wid * 2048 + lane * 32) = w0;
      *(f32x4*)((char*)pcr + wid * 2048 + lane * 32 + 16) = w1;
    }
    __syncthreads();
    {
      float s = 0.f;
#pragma unroll
      for (int g = 0; g < 8; ++g) s += pcr[g * 512 + tid];
      pctx[T * HDIM + tid] = f2bf(s);
    }

    // ---- prep next tile: zbuf swap (epilogue-1 readers are 3 barriers past) --
    if (more) {
      const int bnext = (int)((T + NBLK) >> 5);
      zbuf[tid] = zfull[bnext * HDIM + tid];
    }
    __syncthreads();   // staging writes + zbuf visible; buffers swap
    cur ^= 1;
  }
}

// ---------------- kernel 2: combine partials -> attn (in place) + ctx --------
__global__ void combine(float* __restrict__ attn, const unsigned short* __restrict__ pctx,
                        const float* __restrict__ ml, float* __restrict__ ctx) {
  const int b = blockIdx.x, tid = threadIdx.x;   // 512 threads
  const int lane = tid & 63;
  float m = -1e30f, l = 0.f;
  if (lane < CPB) {
    m = ml[(b * CPB + lane) * 2];
    l = ml[(b * CPB + lane) * 2 + 1];
  }
  float M = m;
#pragma unroll
  for (int off = 1; off < 64; off <<= 1) M = fmaxf(M, __shfl_xor(M, off));
  float le = (lane < CPB) ? l * __expf(m - M) : 0.f;
  float L = le;
#pragma unroll
  for (int off = 1; off < 64; off <<= 1) L += __shfl_xor(L, off);
  const float invL = 1.f / L;

  __shared__ float wc[CPB];
  if (tid < CPB) wc[tid] = __expf(ml[(b * CPB + tid) * 2] - M) * invL;

  // attn rescale in place: attn currently holds raw scores
  float sv[4];
#pragma unroll
  for (int i = 0; i < 4; ++i) sv[i] = attn[(long)b * SEQ + i * 512 + tid];
#pragma unroll
  for (int i = 0; i < 4; ++i)
    attn[(long)b * SEQ + i * 512 + tid] = __expf(sv[i] - M) * invL;

  __syncthreads();
  // ctx[h] = sum_c pctx[c][h] * wc[c]
  float a = 0.f;
#pragma unroll 8
  for (int c = 0; c < CPB; ++c)
    a += bf2f(pctx[(long)(b * CPB + c) * HDIM + tid]) * wc[c];
  ctx[(long)b * HDIM + tid] = a;
}

extern "C" void kernel_launch(void* const* d_in, const int* in_sizes, int n_in,
                              void* d_out, int out_size, void* d_ws, size_t ws_size,
                              hipStream_t stream) {
  const float* enc = (const float*)d_in[0];
  const float* dec = (const float*)d_in[1];
  const float* W1  = (const float*)d_in[2];
  const float* b1  = (const float*)d_in[3];
  const float* W2  = (const float*)d_in[4];
  const float* b2  = (const float*)d_in[5];
  const float* V   = (const float*)d_in[6];
  const float* bv  = (const float*)d_in[7];

  float* out  = (float*)d_out;
  float* ctx  = out;                       // 64*512
  float* attn = out + NB * HDIM;           // 64*2048 (raw scores first, rescaled in place)

  char* ws = (char*)d_ws;
  unsigned short* w1k  = (unsigned short*)ws;                   // 512 KiB (k-step-major)
  float*          zful = (float*)(ws + 524288);                 // 128 KiB
  unsigned short* pctx = (unsigned short*)(ws + 655360);        // 2 MiB  (2048*512 bf16)
  float*          mlb  = (float*)(ws + 2752512);                // 16 KiB (2048*2 f32)
  (void)in_sizes; (void)n_in; (void)out_size; (void)ws_size;

  convert_w1<<<128, 256, 0, stream>>>(W1, w1k);
  zproj<<<dim3(NB, 2), 256, 0, stream>>>(dec, W2, b1, b2, zful);
  gemm_fused<<<NBLK, 512, 0, stream>>>(enc, w1k, zful, V, bv, attn, pctx, mlb);
  combine<<<NB, 512, 0, stream>>>(attn, pctx, mlb, ctx);
}

// Round 6
// 168.580 us; speedup vs baseline: 1.7567x; 1.7567x over previous
//
#include <hip/hip_runtime.h>
#include <hip/hip_bf16.h>

typedef __attribute__((ext_vector_type(4))) float f32x4;
typedef __attribute__((ext_vector_type(8))) short s16x8;
typedef __attribute__((ext_vector_type(4))) unsigned short u16x4;
typedef __attribute__((ext_vector_type(8))) __bf16 bf16x8;

#define HDIM 512
#define SEQ  2048
#define NB   64
#define BM   64
#define NBLK ((NB * SEQ) / BM)   // 2048 blocks
#define CPB  (SEQ / BM)          // 32 chunks per batch

// round-to-nearest-even fp32 -> bf16 bits
static __device__ __forceinline__ unsigned short f2bf(float f) {
  unsigned u = __float_as_uint(f);
  u += 0x7fffu + ((u >> 16) & 1u);
  return (unsigned short)(u >> 16);
}
static __device__ __forceinline__ float bf2f(unsigned short v) {
  return __uint_as_float(((unsigned)v) << 16);
}

static __device__ __forceinline__ f32x4 mfma16(s16x8 a, s16x8 b, f32x4 c) {
  return __builtin_amdgcn_mfma_f32_16x16x32_bf16(
      __builtin_bit_cast(bf16x8, a), __builtin_bit_cast(bf16x8, b), c, 0, 0, 0);
}

// ---------------- kernel 0a: W1 fp32 -> bf16, k-step-major -------------------
// 16B chunk id = kk*2048 + n*4 + r4 holds W1[n][kk*32 + r4*8 .. +8] as bf16.
__global__ void convert_w1(const float* __restrict__ w1,
                           unsigned short* __restrict__ o) {
  int id = blockIdx.x * 256 + threadIdx.x;   // 32768 chunks of 16B
  int kk = id >> 11, n = (id >> 2) & 511, r4 = id & 3;
  const float* src = w1 + (long)n * HDIM + kk * 32 + r4 * 8;
  f32x4 v0 = *(const f32x4*)src;
  f32x4 v1 = *(const f32x4*)(src + 4);
  u16x4 a, b;
  a.x = f2bf(v0.x); a.y = f2bf(v0.y); a.z = f2bf(v0.z); a.w = f2bf(v0.w);
  b.x = f2bf(v1.x); b.y = f2bf(v1.y); b.z = f2bf(v1.z); b.w = f2bf(v1.w);
  unsigned short* dst = o + (long)id * 8;
  *(u16x4*)dst = a;
  *(u16x4*)(dst + 4) = b;
}

// ---------------- kernel 0b: z[b][o] = dec[b]·W2[o] + b2[o] + b1[o] ----------
__global__ void zproj(const float* __restrict__ dec, const float* __restrict__ W2,
                      const float* __restrict__ b1, const float* __restrict__ b2,
                      float* __restrict__ zfull) {
  int b = blockIdx.x, oc = blockIdx.y, tid = threadIdx.x;
  int o = oc * 256 + tid;
  __shared__ float d_s[HDIM];
  d_s[tid] = dec[b * HDIM + tid];
  d_s[tid + 256] = dec[b * HDIM + tid + 256];
  __syncthreads();
  const float* w = W2 + (long)o * HDIM;
  float s = 0.f;
#pragma unroll 4
  for (int k = 0; k < HDIM; k += 4) {
    f32x4 v = *(const f32x4*)(w + k);
    s += v.x * d_s[k] + v.y * d_s[k + 1] + v.z * d_s[k + 2] + v.w * d_s[k + 3];
  }
  zfull[b * HDIM + o] = s + b1[o] + b2[o];
}

// ------ kernel 1: fused GEMM + tanh + V-dot + local softmax + partial ctx ----
// 2 blocks/CU (LDS-limited); VGPR budget 256 so the B register double-buffer
// actually lives in registers (R4's (512,4) capped VGPR=128 and serialized it).
__global__ __launch_bounds__(512, 2)
void gemm_fused(const float* __restrict__ enc, const unsigned short* __restrict__ w1k,
                const float* __restrict__ zfull, const float* __restrict__ V,
                const float* __restrict__ bv, float* __restrict__ scores,
                unsigned short* __restrict__ pctx, float* __restrict__ ml) {
  __shared__ __align__(16) char pool[71936];
  unsigned short* Asm = (unsigned short*)pool;            // 64 KiB bf16 tile
  float* zbuf = (float*)(pool + 65536);                   // 512 f
  float* vbuf = (float*)(pool + 67584);                   // 512 f
  float* red  = (float*)(pool + 69632);                   // 8*64 f
  float* plds = (float*)(pool + 71680);                   // 64 f
  float* pcr  = (float*)pool;                             // overlays A after reads

  const int tid = threadIdx.x;
  const int wid = tid >> 6;
  const int lane = tid & 63;
  const long m0 = (long)blockIdx.x * BM;
  const int b = (int)(m0 >> 11);

  zbuf[tid] = zfull[b * HDIM + tid];
  vbuf[tid] = V[tid];

  // ---- phase 0: stage A tile (fp32 -> bf16, XOR-swizzled) ----
  {
    const float* Ablk = enc + m0 * HDIM;
    const int qf32 = tid & 127;
    const int rbase = tid >> 7;
    const int q = qf32 >> 1, half = qf32 & 1;
#pragma unroll
    for (int j = 0; j < 16; ++j) {
      const int row = j * 4 + rbase;
      f32x4 v = *(const f32x4*)(Ablk + (long)row * HDIM + qf32 * 4);
      u16x4 pk;
      pk.x = f2bf(v.x); pk.y = f2bf(v.y); pk.z = f2bf(v.z); pk.w = f2bf(v.w);
      *(u16x4*)((char*)Asm + row * 1024 + ((q ^ (row & 7)) * 16) + half * 8) = pk;
    }
  }

  const int r4 = lane >> 4, c15 = lane & 15, c7 = c15 & 7;
  const int rs = r4 ^ (c7 & 3), kb = c7 >> 2;
  const char* Ab = (const char*)Asm;
  const int a0 = c15 * 1024 + rs * 16 + kb * 64;        // even kk
  const int a1 = c15 * 1024 + rs * 16 + (kb ^ 1) * 64;  // odd  kk
  const unsigned short* bp = w1k + (wid * 64 + c15) * 32 + r4 * 8;

  f32x4 acc[4][4] = {};
  s16x8 bA[4], bB[4];

  // prefetch B for kk=0 (drains at the barrier, ready for loop)
#pragma unroll
  for (int nf = 0; nf < 4; ++nf) bA[nf] = *(const s16x8*)(bp + nf * 512);
  __syncthreads();

  // ---- K-loop: barrier-free, explicit 1-deep B register double-buffer ----
#pragma unroll
  for (int kt = 0; kt < 8; ++kt) {
    const int k0 = 2 * kt, k1 = 2 * kt + 1;
    // issue B(k1) while computing with bA(k0)
#pragma unroll
    for (int nf = 0; nf < 4; ++nf)
      bB[nf] = *(const s16x8*)(bp + k1 * 16384 + nf * 512);
    {
      s16x8 af[4];
      const int ab = a0 + kt * 128;
#pragma unroll
      for (int mf = 0; mf < 4; ++mf)
        af[mf] = *(const s16x8*)(Ab + ab + mf * 16384);
#pragma unroll
      for (int mf = 0; mf < 4; ++mf)
#pragma unroll
        for (int nf = 0; nf < 4; ++nf)
          acc[mf][nf] = mfma16(af[mf], bA[nf], acc[mf][nf]);
    }
    // issue B(k0+2) while computing with bB(k1)
    if (kt < 7) {
#pragma unroll
      for (int nf = 0; nf < 4; ++nf)
        bA[nf] = *(const s16x8*)(bp + (k0 + 2) * 16384 + nf * 512);
    }
    {
      s16x8 af[4];
      const int ab = a1 + kt * 128;
#pragma unroll
      for (int mf = 0; mf < 4; ++mf)
        af[mf] = *(const s16x8*)(Ab + ab + mf * 16384);
#pragma unroll
      for (int mf = 0; mf < 4; ++mf)
#pragma unroll
        for (int nf = 0; nf < 4; ++nf)
          acc[mf][nf] = mfma16(af[mf], bB[nf], acc[mf][nf]);
    }
  }

  // ---- epilogue 1: scores[m] = sum_n tanh(acc + z[n]) * V[n] + bv ----
  // C/D layout (16x16x32): col = lane&15, row = (lane>>4)*4 + j   [m89/m91]
#pragma unroll
  for (int mf = 0; mf < 4; ++mf) {
#pragma unroll
    for (int j = 0; j < 4; ++j) {
      float s = 0.f;
#pragma unroll
      for (int nf = 0; nf < 4; ++nf) {
        const int n = wid * 64 + nf * 16 + c15;
        float x = acc[mf][nf][j] + zbuf[n];
        float e = __expf(2.f * x);
        float t = 1.f - 2.f * __builtin_amdgcn_rcpf(e + 1.f);  // tanh(x)
        s += t * vbuf[n];
      }
      s += __shfl_xor(s, 1); s += __shfl_xor(s, 2);
      s += __shfl_xor(s, 4); s += __shfl_xor(s, 8);
      if (c15 == 0) red[wid * BM + mf * 16 + r4 * 4 + j] = s;
    }
  }
  __syncthreads();

  // ---- epilogue 2: wave 0 finishes scores + local softmax stats ----
  if (tid < BM) {
    float s = 0.f;
#pragma unroll
    for (int w = 0; w < 8; ++w) s += red[w * BM + tid];
    s += bv[0];
    scores[m0 + tid] = s;                       // raw score
    float mc = s;
#pragma unroll
    for (int off = 1; off < 64; off <<= 1) mc = fmaxf(mc, __shfl_xor(mc, off));
    float p = __expf(s - mc);
    plds[tid] = p;
    float lc = p;
#pragma unroll
    for (int off = 1; off < 64; off <<= 1) lc += __shfl_xor(lc, off);
    if (tid == 0) { ml[blockIdx.x * 2] = mc; ml[blockIdx.x * 2 + 1] = lc; }
  }
  __syncthreads();

  // ---- epilogue 3: pctx[h] = sum_s p[s]*A[s][h], vector LDS reads ----
  // thread (wid,lane): rows r = wid*8+rr; phys chunk lane^rr at row r is
  // logical chunk lane (p = q ^ (r&7), rr = r&7) -> h = lane*8 + e.
  float c8[8] = {};
#pragma unroll
  for (int rr = 0; rr < 8; ++rr) {
    const int r = wid * 8 + rr;
    s16x8 v = *(const s16x8*)(Ab + r * 1024 + ((lane ^ rr) * 16));
    const float p = plds[r];
#pragma unroll
    for (int e = 0; e < 8; ++e)
      c8[e] += p * bf2f((unsigned short)v[e]);
  }
  __syncthreads();   // all A reads done; safe to overlay pcr on A region
  {
    f32x4 w0, w1;
    w0.x = c8[0]; w0.y = c8[1]; w0.z = c8[2]; w0.w = c8[3];
    w1.x = c8[4]; w1.y = c8[5]; w1.z = c8[6]; w1.w = c8[7];
    *(f32x4*)((char*)pcr + wid * 2048 + lane * 32) = w0;
    *(f32x4*)((char*)pcr + wid * 2048 + lane * 32 + 16) = w1;
  }
  __syncthreads();
  {
    float s = 0.f;
#pragma unroll
    for (int g = 0; g < 8; ++g) s += pcr[g * 512 + tid];
    pctx[(long)blockIdx.x * HDIM + tid] = f2bf(s);
  }
}

// ---------------- kernel 2: combine partials -> attn (in place) + ctx --------
__global__ void combine(float* __restrict__ attn, const unsigned short* __restrict__ pctx,
                        const float* __restrict__ ml, float* __restrict__ ctx) {
  const int b = blockIdx.x, tid = threadIdx.x;   // 512 threads
  const int lane = tid & 63;
  float m = -1e30f, l = 0.f;
  if (lane < CPB) {
    m = ml[(b * CPB + lane) * 2];
    l = ml[(b * CPB + lane) * 2 + 1];
  }
  float M = m;
#pragma unroll
  for (int off = 1; off < 64; off <<= 1) M = fmaxf(M, __shfl_xor(M, off));
  float le = (lane < CPB) ? l * __expf(m - M) : 0.f;
  float L = le;
#pragma unroll
  for (int off = 1; off < 64; off <<= 1) L += __shfl_xor(L, off);
  const float invL = 1.f / L;

  __shared__ float wc[CPB];
  if (tid < CPB) wc[tid] = __expf(ml[(b * CPB + tid) * 2] - M) * invL;

  // attn rescale in place: attn currently holds raw scores
  float sv[4];
#pragma unroll
  for (int i = 0; i < 4; ++i) sv[i] = attn[(long)b * SEQ + i * 512 + tid];
#pragma unroll
  for (int i = 0; i < 4; ++i)
    attn[(long)b * SEQ + i * 512 + tid] = __expf(sv[i] - M) * invL;

  __syncthreads();
  // ctx[h] = sum_c pctx[c][h] * wc[c]
  float a = 0.f;
#pragma unroll 8
  for (int c = 0; c < CPB; ++c)
    a += bf2f(pctx[(long)(b * CPB + c) * HDIM + tid]) * wc[c];
  ctx[(long)b * HDIM + tid] = a;
}

extern "C" void kernel_launch(void* const* d_in, const int* in_sizes, int n_in,
                              void* d_out, int out_size, void* d_ws, size_t ws_size,
                              hipStream_t stream) {
  const float* enc = (const float*)d_in[0];
  const float* dec = (const float*)d_in[1];
  const float* W1  = (const float*)d_in[2];
  const float* b1  = (const float*)d_in[3];
  const float* W2  = (const float*)d_in[4];
  const float* b2  = (const float*)d_in[5];
  const float* V   = (const float*)d_in[6];
  const float* bv  = (const float*)d_in[7];

  float* out  = (float*)d_out;
  float* ctx  = out;                       // 64*512
  float* attn = out + NB * HDIM;           // 64*2048 (raw scores first, rescaled in place)

  char* ws = (char*)d_ws;
  unsigned short* w1k  = (unsigned short*)ws;                   // 512 KiB (k-step-major)
  float*          zful = (float*)(ws + 524288);                 // 128 KiB
  unsigned short* pctx = (unsigned short*)(ws + 655360);        // 2 MiB  (2048*512 bf16)
  float*          mlb  = (float*)(ws + 2752512);                // 16 KiB (2048*2 f32)
  (void)in_sizes; (void)n_in; (void)out_size; (void)ws_size;

  convert_w1<<<128, 256, 0, stream>>>(W1, w1k);
  zproj<<<dim3(NB, 2), 256, 0, stream>>>(dec, W2, b1, b2, zful);
  gemm_fused<<<NBLK, 512, 0, stream>>>(enc, w1k, zful, V, bv, attn, pctx, mlb);
  combine<<<NB, 512, 0, stream>>>(attn, pctx, mlb, ctx);
}

// Round 7
// 123.893 us; speedup vs baseline: 2.3903x; 1.3607x over previous
//
#include <hip/hip_runtime.h>
#include <hip/hip_bf16.h>

typedef __attribute__((ext_vector_type(4))) float f32x4;
typedef __attribute__((ext_vector_type(8))) short s16x8;
typedef __attribute__((ext_vector_type(4))) unsigned short u16x4;
typedef __attribute__((ext_vector_type(8))) __bf16 bf16x8;

#define HDIM 512
#define SEQ  2048
#define NB   64
#define BM   64
#define NBLK ((NB * SEQ) / BM)   // 2048 blocks
#define CPB  (SEQ / BM)          // 32 chunks per batch

// round-to-nearest-even fp32 -> bf16 bits
static __device__ __forceinline__ unsigned short f2bf(float f) {
  unsigned u = __float_as_uint(f);
  u += 0x7fffu + ((u >> 16) & 1u);
  return (unsigned short)(u >> 16);
}
static __device__ __forceinline__ float bf2f(unsigned short v) {
  return __uint_as_float(((unsigned)v) << 16);
}

static __device__ __forceinline__ f32x4 mfma16(s16x8 a, s16x8 b, f32x4 c) {
  return __builtin_amdgcn_mfma_f32_16x16x32_bf16(
      __builtin_bit_cast(bf16x8, a), __builtin_bit_cast(bf16x8, b), c, 0, 0, 0);
}

// 4 B-fragment loads for one k-step: SGPR base sp, shared voffset, imm per nf.
// asm volatile: compiler cannot sink/merge; completion managed by manual vmcnt.
#define BLOADG(dst, sp)                                                        \
  do {                                                                         \
    asm volatile("global_load_dwordx4 %0, %1, %2 offset:0"                     \
                 : "=&v"((dst)[0]) : "v"(voff), "s"(sp));                      \
    asm volatile("global_load_dwordx4 %0, %1, %2 offset:1024"                  \
                 : "=&v"((dst)[1]) : "v"(voff), "s"(sp));                      \
    asm volatile("global_load_dwordx4 %0, %1, %2 offset:2048"                  \
                 : "=&v"((dst)[2]) : "v"(voff), "s"(sp));                      \
    asm volatile("global_load_dwordx4 %0, %1, %2 offset:3072"                  \
                 : "=&v"((dst)[3]) : "v"(voff), "s"(sp));                      \
  } while (0)

// ---------------- kernel 0a: W1 fp32 -> bf16, k-step-major -------------------
// 16B chunk id = kk*2048 + n*4 + r4 holds W1[n][kk*32 + r4*8 .. +8] as bf16.
__global__ void convert_w1(const float* __restrict__ w1,
                           unsigned short* __restrict__ o) {
  int id = blockIdx.x * 256 + threadIdx.x;   // 32768 chunks of 16B
  int kk = id >> 11, n = (id >> 2) & 511, r4 = id & 3;
  const float* src = w1 + (long)n * HDIM + kk * 32 + r4 * 8;
  f32x4 v0 = *(const f32x4*)src;
  f32x4 v1 = *(const f32x4*)(src + 4);
  u16x4 a, b;
  a.x = f2bf(v0.x); a.y = f2bf(v0.y); a.z = f2bf(v0.z); a.w = f2bf(v0.w);
  b.x = f2bf(v1.x); b.y = f2bf(v1.y); b.z = f2bf(v1.z); b.w = f2bf(v1.w);
  unsigned short* dst = o + (long)id * 8;
  *(u16x4*)dst = a;
  *(u16x4*)(dst + 4) = b;
}

// ---------------- kernel 0b: z[b][o] = dec[b]·W2[o] + b2[o] + b1[o] ----------
__global__ void zproj(const float* __restrict__ dec, const float* __restrict__ W2,
                      const float* __restrict__ b1, const float* __restrict__ b2,
                      float* __restrict__ zfull) {
  int b = blockIdx.x, oc = blockIdx.y, tid = threadIdx.x;
  int o = oc * 256 + tid;
  __shared__ float d_s[HDIM];
  d_s[tid] = dec[b * HDIM + tid];
  d_s[tid + 256] = dec[b * HDIM + tid + 256];
  __syncthreads();
  const float* w = W2 + (long)o * HDIM;
  float s = 0.f;
#pragma unroll 4
  for (int k = 0; k < HDIM; k += 4) {
    f32x4 v = *(const f32x4*)(w + k);
    s += v.x * d_s[k] + v.y * d_s[k + 1] + v.z * d_s[k + 2] + v.w * d_s[k + 3];
  }
  zfull[b * HDIM + o] = s + b1[o] + b2[o];
}

// ------ kernel 1: fused GEMM + tanh + V-dot + local softmax + partial ctx ----
// 2 blocks/CU. B loads are inline-asm with counted vmcnt (depth-1 register
// double buffer the compiler can't collapse); waves k-rotated to desync L2.
__global__ __launch_bounds__(512, 4)
void gemm_fused(const float* __restrict__ enc, const unsigned short* __restrict__ w1k,
                const float* __restrict__ zfull, const float* __restrict__ V,
                const float* __restrict__ bv, float* __restrict__ scores,
                unsigned short* __restrict__ pctx, float* __restrict__ ml) {
  __shared__ __align__(16) char pool[71936];
  unsigned short* Asm = (unsigned short*)pool;            // 64 KiB bf16 tile
  float* zbuf = (float*)(pool + 65536);                   // 512 f
  float* vbuf = (float*)(pool + 67584);                   // 512 f
  float* red  = (float*)(pool + 69632);                   // 8*64 f
  float* plds = (float*)(pool + 71680);                   // 64 f
  float* pcr  = (float*)pool;                             // overlays A after reads

  const int tid = threadIdx.x;
  const int wid = tid >> 6;
  const int lane = tid & 63;
  const long m0 = (long)blockIdx.x * BM;
  const int b = (int)(m0 >> 11);

  zbuf[tid] = zfull[b * HDIM + tid];
  vbuf[tid] = V[tid];

  // ---- phase 0: stage A tile (fp32 -> bf16, XOR-swizzled) ----
  {
    const float* Ablk = enc + m0 * HDIM;
    const int qf32 = tid & 127;
    const int rbase = tid >> 7;
    const int q = qf32 >> 1, half = qf32 & 1;
#pragma unroll
    for (int j = 0; j < 16; ++j) {
      const int row = j * 4 + rbase;
      f32x4 v = *(const f32x4*)(Ablk + (long)row * HDIM + qf32 * 4);
      u16x4 pk;
      pk.x = f2bf(v.x); pk.y = f2bf(v.y); pk.z = f2bf(v.z); pk.w = f2bf(v.w);
      *(u16x4*)((char*)Asm + row * 1024 + ((q ^ (row & 7)) * 16) + half * 8) = pk;
    }
  }

  const int r4 = lane >> 4, c15 = lane & 15, c7 = c15 & 7;
  const char* Ab = (const char*)Asm;
  const unsigned voff = (unsigned)((wid * 64 + c15) * 64 + r4 * 16);
  const int widu = __builtin_amdgcn_readfirstlane(wid);   // uniform for SGPR math

  f32x4 acc[4][4] = {};
  s16x8 bX[4], bY[4];

  __syncthreads();   // A tile + zbuf/vbuf visible (drains staging vmem too)

  // prefetch B group for this wave's first k-step (rotated)
  BLOADG(bX, w1k + ((widu & 15) * 16384));

  // ---- K-loop: barrier-free; asm depth-1 B pipeline with counted vmcnt ----
#pragma unroll
  for (int kk = 0; kk < 16; ++kk) {
    const int ke = (kk + widu) & 15;      // this wave's k-step this iteration
    s16x8* cur = (kk & 1) ? bY : bX;      // compile-time under full unroll
    s16x8* nxt = (kk & 1) ? bX : bY;

    // A fragments for ke (LDS; compiler handles lgkmcnt, may hoist earlier)
    s16x8 af[4];
    const int abase = c15 * 1024 + (((ke * 4 + r4) ^ c7) * 16);
#pragma unroll
    for (int mf = 0; mf < 4; ++mf)
      af[mf] = *(const s16x8*)(Ab + abase + mf * 16384);

    if (kk < 15) {
      const unsigned short* sp = w1k + ((((kk + 1) + widu) & 15) * 16384);
      BLOADG(nxt, sp);
      asm volatile("s_waitcnt vmcnt(4)");   // cur group done; nxt in flight
    } else {
      asm volatile("s_waitcnt vmcnt(0)");
    }
    __builtin_amdgcn_sched_barrier(0);      // nothing crosses the wait

#pragma unroll
    for (int mf = 0; mf < 4; ++mf)
#pragma unroll
      for (int nf = 0; nf < 4; ++nf)
        acc[mf][nf] = mfma16(af[mf], cur[nf], acc[mf][nf]);
  }

  // ---- epilogue 1: scores[m] = sum_n tanh(acc + z[n]) * V[n] + bv ----
  // C/D layout (16x16x32): col = lane&15, row = (lane>>4)*4 + j   [m89/m91]
  float zr[4], vr[4];
#pragma unroll
  for (int nf = 0; nf < 4; ++nf) {
    const int n = wid * 64 + nf * 16 + c15;
    zr[nf] = zbuf[n];
    vr[nf] = vbuf[n];
  }
#pragma unroll
  for (int mf = 0; mf < 4; ++mf) {
#pragma unroll
    for (int j = 0; j < 4; ++j) {
      float s = 0.f;
#pragma unroll
      for (int nf = 0; nf < 4; ++nf) {
        float x = acc[mf][nf][j] + zr[nf];
        float e = __expf(2.f * x);
        float t = 1.f - 2.f * __builtin_amdgcn_rcpf(e + 1.f);  // tanh(x)
        s += t * vr[nf];
      }
      s += __shfl_xor(s, 1); s += __shfl_xor(s, 2);
      s += __shfl_xor(s, 4); s += __shfl_xor(s, 8);
      if (c15 == 0) red[wid * BM + mf * 16 + r4 * 4 + j] = s;
    }
  }
  __syncthreads();

  // ---- epilogue 2: wave 0 finishes scores + local softmax stats ----
  if (tid < BM) {
    float s = 0.f;
#pragma unroll
    for (int w = 0; w < 8; ++w) s += red[w * BM + tid];
    s += bv[0];
    scores[m0 + tid] = s;                       // raw score
    float mc = s;
#pragma unroll
    for (int off = 1; off < 64; off <<= 1) mc = fmaxf(mc, __shfl_xor(mc, off));
    float p = __expf(s - mc);
    plds[tid] = p;
    float lc = p;
#pragma unroll
    for (int off = 1; off < 64; off <<= 1) lc += __shfl_xor(lc, off);
    if (tid == 0) { ml[blockIdx.x * 2] = mc; ml[blockIdx.x * 2 + 1] = lc; }
  }
  __syncthreads();

  // ---- epilogue 3: pctx[h] = sum_s p[s]*A[s][h], vector LDS reads ----
  float c8[8] = {};
#pragma unroll
  for (int rr = 0; rr < 8; ++rr) {
    const int r = wid * 8 + rr;
    s16x8 v = *(const s16x8*)(Ab + r * 1024 + ((lane ^ rr) * 16));
    const float p = plds[r];
#pragma unroll
    for (int e = 0; e < 8; ++e)
      c8[e] += p * bf2f((unsigned short)v[e]);
  }
  __syncthreads();   // all A reads done; safe to overlay pcr on A region
  {
    f32x4 w0, w1;
    w0.x = c8[0]; w0.y = c8[1]; w0.z = c8[2]; w0.w = c8[3];
    w1.x = c8[4]; w1.y = c8[5]; w1.z = c8[6]; w1.w = c8[7];
    *(f32x4*)((char*)pcr + wid * 2048 + lane * 32) = w0;
    *(f32x4*)((char*)pcr + wid * 2048 + lane * 32 + 16) = w1;
  }
  __syncthreads();
  {
    float s = 0.f;
#pragma unroll
    for (int g = 0; g < 8; ++g) s += pcr[g * 512 + tid];
    pctx[(long)blockIdx.x * HDIM + tid] = f2bf(s);
  }
}

// ---------------- kernel 2: combine partials -> attn (in place) + ctx --------
__global__ void combine(float* __restrict__ attn, const unsigned short* __restrict__ pctx,
                        const float* __restrict__ ml, float* __restrict__ ctx) {
  const int b = blockIdx.x, tid = threadIdx.x;   // 512 threads
  const int lane = tid & 63;
  float m = -1e30f, l = 0.f;
  if (lane < CPB) {
    m = ml[(b * CPB + lane) * 2];
    l = ml[(b * CPB + lane) * 2 + 1];
  }
  float M = m;
#pragma unroll
  for (int off = 1; off < 64; off <<= 1) M = fmaxf(M, __shfl_xor(M, off));
  float le = (lane < CPB) ? l * __expf(m - M) : 0.f;
  float L = le;
#pragma unroll
  for (int off = 1; off < 64; off <<= 1) L += __shfl_xor(L, off);
  const float invL = 1.f / L;

  __shared__ float wc[CPB];
  if (tid < CPB) wc[tid] = __expf(ml[(b * CPB + tid) * 2] - M) * invL;

  // attn rescale in place: attn currently holds raw scores
  float sv[4];
#pragma unroll
  for (int i = 0; i < 4; ++i) sv[i] = attn[(long)b * SEQ + i * 512 + tid];
#pragma unroll
  for (int i = 0; i < 4; ++i)
    attn[(long)b * SEQ + i * 512 + tid] = __expf(sv[i] - M) * invL;

  __syncthreads();
  // ctx[h] = sum_c pctx[c][h] * wc[c]
  float a = 0.f;
#pragma unroll 8
  for (int c = 0; c < CPB; ++c)
    a += bf2f(pctx[(long)(b * CPB + c) * HDIM + tid]) * wc[c];
  ctx[(long)b * HDIM + tid] = a;
}

extern "C" void kernel_launch(void* const* d_in, const int* in_sizes, int n_in,
                              void* d_out, int out_size, void* d_ws, size_t ws_size,
                              hipStream_t stream) {
  const float* enc = (const float*)d_in[0];
  const float* dec = (const float*)d_in[1];
  const float* W1  = (const float*)d_in[2];
  const float* b1  = (const float*)d_in[3];
  const float* W2  = (const float*)d_in[4];
  const float* b2  = (const float*)d_in[5];
  const float* V   = (const float*)d_in[6];
  const float* bv  = (const float*)d_in[7];

  float* out  = (float*)d_out;
  float* ctx  = out;                       // 64*512
  float* attn = out + NB * HDIM;           // 64*2048 (raw scores first, rescaled in place)

  char* ws = (char*)d_ws;
  unsigned short* w1k  = (unsigned short*)ws;                   // 512 KiB (k-step-major)
  float*          zful = (float*)(ws + 524288);                 // 128 KiB
  unsigned short* pctx = (unsigned short*)(ws + 655360);        // 2 MiB  (2048*512 bf16)
  float*          mlb  = (float*)(ws + 2752512);                // 16 KiB (2048*2 f32)
  (void)in_sizes; (void)n_in; (void)out_size; (void)ws_size;

  convert_w1<<<128, 256, 0, stream>>>(W1, w1k);
  zproj<<<dim3(NB, 2), 256, 0, stream>>>(dec, W2, b1, b2, zful);
  gemm_fused<<<NBLK, 512, 0, stream>>>(enc, w1k, zful, V, bv, attn, pctx, mlb);
  combine<<<NB, 512, 0, stream>>>(attn, pctx, mlb, ctx);
}